// Round 8
// baseline (149.501 us; speedup 1.0000x reference)
//
#include <hip/hip_runtime.h>
#include <math.h>
#include <complex>

// SO3 irrep rotation: out = Dy(alpha) J Dy(beta) J Dy(gamma) x, per irrep l=0..8, mul=64.
// Layout x: [B][sum_l (2l+1)*64], block l at float offset 64*l*l, element (b,i,m) at i*64+m.
// R15 = R7 (the fastest variant measured: 136.9 us) with EXACTLY ONE change:
//   stores are regular cached writes instead of __builtin_nontemporal_store.
// Rationale: R8-R14 falsified VALU work (2.3x), LDS op count (3.5x), barriers, load
// pipelining, and store width as limiters (all land 137-145 us). The never-tested
// variable is the NT hint itself: NT = evict-first/no-allocate, forcing eager drain
// of each 256B wave-store toward DRAM; cached writes let L2/L3 absorb the stream and
// drain lazily, overlapping replay N's writeback with replay N+1's reads in the
// steady-state graph loop. Risk (measurable): write allocation evicts x from L3 ->
// FETCH_SIZE rises from 167 MB toward 340 MB. The counter delta decides:
//   - faster + FETCH flat  -> NT was the limiter, keep cached stores
//   - slower + FETCH ~300M -> L3 eviction dominates, NT was right; pattern roofline
//   - null                 -> mixed-stream ~4.8 TB/s is the measured ceiling -> ROOFLINE
// Everything else bit-identical to R7 (kernarg J, Chebyshev trig, per-lane blocks).

#define LMAX 8
#define BATCH 16384
#define DIM 5184

__host__ __device__ constexpr int joff_u(int l) {
    int o = 0;
    for (int k = 0; k < l; ++k) { int dk = 2 * k + 1; o += dk * dk; }
    return o;
}
#define NJ 969  // joff_u(9)

struct JPack { float v[NJ]; };

// ---------------- host-side J computation ----------------
// J_l = expm(pi/sqrt(2) * (Xx + Xy)) in the real spherical-harmonic basis,
// ported 1:1 from the reference's generator construction (validated R1-R14).
static void compute_J_host(JPack* jp) {
    for (int l = 0; l <= LMAX; ++l) {
        const int d = 2 * l + 1;
        std::complex<double> q[289], Ac[289], T1[289];
        double A[289], E[289], Tm[289], P[289];
        const double is2 = 1.0 / std::sqrt(2.0);
        static const double pr[4] = {1.0, 0.0, -1.0, 0.0};
        static const double pim[4] = {0.0, -1.0, 0.0, 1.0};
        const int ph = l & 3;
        for (int i = 0; i < d; ++i) {
            for (int j = 0; j < d; ++j) {
                double re = 0.0, im = 0.0;
                const int mm = i - l;
                if (mm < 0) {
                    if (j == l - mm) re = is2;
                    if (j == l + mm) im = -is2;
                } else if (mm == 0) {
                    if (j == l) re = 1.0;
                } else {
                    const double sgn = (mm & 1) ? -1.0 : 1.0;
                    if (j == l + mm) re = sgn * is2;
                    if (j == l - mm) im = sgn * is2;
                }
                q[i * d + j] = std::complex<double>(re * pr[ph] - im * pim[ph],
                                                    re * pim[ph] + im * pr[ph]);
                double xr = 0.0;
                if (j == i - 1) {
                    const double m = (double)(i - 1 - l);
                    xr += -0.5 * std::sqrt((double)l * (l + 1) - m * (m + 1));
                }
                if (j == i + 1) {
                    const double m = (double)(i - l + 1);
                    xr += 0.5 * std::sqrt((double)l * (l + 1) - m * (m - 1));
                }
                Ac[i * d + j] = std::complex<double>(xr, (i == j) ? (double)(i - l) : 0.0);
            }
        }
        for (int i = 0; i < d; ++i)
            for (int j = 0; j < d; ++j) {
                std::complex<double> s = 0.0;
                for (int k = 0; k < d; ++k) s += Ac[i * d + k] * q[k * d + j];
                T1[i * d + j] = s;
            }
        for (int i = 0; i < d; ++i)
            for (int j = 0; j < d; ++j) {
                std::complex<double> s = 0.0;
                for (int k = 0; k < d; ++k) s += std::conj(q[k * d + i]) * T1[k * d + j];
                A[i * d + j] = s.real() * (M_PI / std::sqrt(2.0));
            }
        double mx = 0.0;
        for (int i = 0; i < d; ++i) {
            double s = 0.0;
            for (int k = 0; k < d; ++k) s += std::fabs(A[i * d + k]);
            mx = std::fmax(mx, s);
        }
        int sh = 0;
        while (mx > 0.25 && sh < 60) { mx *= 0.5; ++sh; }
        const double sc = std::ldexp(1.0, -sh);
        for (int t = 0; t < d * d; ++t) A[t] *= sc;
        for (int i = 0; i < d; ++i)
            for (int j = 0; j < d; ++j) E[i * d + j] = Tm[i * d + j] = (i == j) ? 1.0 : 0.0;
        for (int kk = 1; kk <= 16; ++kk) {
            for (int i = 0; i < d; ++i)
                for (int j = 0; j < d; ++j) {
                    double s = 0.0;
                    for (int k = 0; k < d; ++k) s += Tm[i * d + k] * A[k * d + j];
                    P[i * d + j] = s / (double)kk;
                }
            for (int t = 0; t < d * d; ++t) { Tm[t] = P[t]; E[t] += P[t]; }
        }
        for (int q2 = 0; q2 < sh; ++q2) {
            for (int i = 0; i < d; ++i)
                for (int j = 0; j < d; ++j) {
                    double s = 0.0;
                    for (int k = 0; k < d; ++k) s += E[i * d + k] * E[k * d + j];
                    P[i * d + j] = s;
                }
            for (int t = 0; t < d * d; ++t) E[t] = P[t];
        }
        for (int i = 0; i < d; ++i)
            for (int j = 0; j < d; ++j)
                jp->v[joff_u(l) + i * d + j] = (float)E[i * d + j];
    }
}

// ---------------- main kernel ----------------
// rotY in place; trig by ascending Chebyshev recurrence (2 live regs).
template <int L>
__device__ __forceinline__ void rotY(float* v, float c1, float s1) {
    if constexpr (L >= 1) {
        float ck = c1, sk = s1;
#pragma unroll
        for (int k = 1; k <= L; ++k) {
            const int i = L - k, r = L + k;
            const float vi = v[i], vr = v[r];
            v[i] = ck * vi + sk * vr;
            v[r] = ck * vr - sk * vi;
            if (k < L) {
                const float cn = ck * c1 - sk * s1;
                const float sn = sk * c1 + ck * s1;
                ck = cn; sk = sn;
            }
        }
    }
}

// out[i] = sum_j J[i,j]*a[j]; J from kernarg (invariant) -> s_load/SGPR operand.
template <int L>
__device__ __forceinline__ void jmul(float* __restrict__ out, const float* __restrict__ a,
                                     const JPack& jp) {
    constexpr int D = 2 * L + 1;
    constexpr int OFF = joff_u(L);
#pragma unroll
    for (int i = 0; i < D; ++i) {
        float s = 0.f;
#pragma unroll
        for (int j = 0; j < D; ++j) s += jp.v[OFF + i * D + j] * a[j];
        out[i] = s;
    }
}

// One l-block: load burst -> rot/J/rot/J/rot -> CACHED store burst. Nothing live across calls.
template <int L>
__device__ __forceinline__ void process(const float* __restrict__ xb, float* __restrict__ ob,
                                        const JPack& jp,
                                        float cg, float sg, float cb, float sb,
                                        float ca, float sa) {
    constexpr int D = 2 * L + 1;
    const float* p = xb + 64 * L * L;
    float A[D], B[D];
#pragma unroll
    for (int i = 0; i < D; ++i) A[i] = p[i * 64];   // cached loads (L3 reuse)
    rotY<L>(A, cg, sg);
    jmul<L>(B, A, jp);
    rotY<L>(B, cb, sb);
    jmul<L>(A, B, jp);
    rotY<L>(A, ca, sa);
    float* o = ob + 64 * L * L;
#pragma unroll
    for (int i = 0; i < D; ++i) o[i * 64] = A[i];   // R15: cached store (was NT) — the ONE change
}

__global__ __launch_bounds__(256) void rot_main(const float* __restrict__ gamma,
                                                const float* __restrict__ beta,
                                                const float* __restrict__ alpha,
                                                const float* __restrict__ x,
                                                float* __restrict__ out,
                                                const JPack jp) {
    const int wave = threadIdx.x >> 6;
    const int lane = threadIdx.x & 63;
    const int b = blockIdx.x * 4 + wave;   // one batch row per wave

    const float gm = gamma[b], bt = beta[b], al = alpha[b];
    float sg, cg, sb, cb, sa, ca;
    __sincosf(gm, &sg, &cg);
    __sincosf(bt, &sb, &cb);
    __sincosf(al, &sa, &ca);

    const float* xb = x + (size_t)b * DIM + lane;
    float* ob = out + (size_t)b * DIM + lane;

    process<0>(xb, ob, jp, cg, sg, cb, sb, ca, sa);
    process<1>(xb, ob, jp, cg, sg, cb, sb, ca, sa);
    process<2>(xb, ob, jp, cg, sg, cb, sb, ca, sa);
    process<3>(xb, ob, jp, cg, sg, cb, sb, ca, sa);
    process<4>(xb, ob, jp, cg, sg, cb, sb, ca, sa);
    process<5>(xb, ob, jp, cg, sg, cb, sb, ca, sa);
    process<6>(xb, ob, jp, cg, sg, cb, sb, ca, sa);
    process<7>(xb, ob, jp, cg, sg, cb, sb, ca, sa);
    process<8>(xb, ob, jp, cg, sg, cb, sb, ca, sa);
}

extern "C" void kernel_launch(void* const* d_in, const int* in_sizes, int n_in,
                              void* d_out, int out_size, void* d_ws, size_t ws_size,
                              hipStream_t stream) {
    const float* gamma = (const float*)d_in[0];
    const float* beta  = (const float*)d_in[1];
    const float* alpha = (const float*)d_in[2];
    const float* x     = (const float*)d_in[3];
    float* out = (float*)d_out;

    JPack jp;
    compute_J_host(&jp);   // deterministic, pure host math

    hipLaunchKernelGGL(rot_main, dim3(BATCH / 4), dim3(256), 0, stream,
                       gamma, beta, alpha, x, out, jp);
}